// Round 5
// baseline (352.628 us; speedup 1.0000x reference)
//
#include <hip/hip_runtime.h>
#include <math.h>

#define ROWN 10000
#define COLN 4096
#define DIM 16
#define EN 1000000
#define BIGF 100000.0f

// per-column record: 48 float4 (768 B)
//  [0]        = (1, t, t^2/2, t^3/6)
//  [1..40]    = L^T ragged quads: for k=0..15, quads q=k/4..3, elem j = L[4q+j][k]
//  [41..44]   = z_cols[c] (16 floats)
//  [45]       = (gamma_col, 0, 0, 0)
#define RECQ 48
#define RECF (RECQ * 4)

#define NBH 256      // histogram chunks (own tiny kernel)
#define CHH 3907     // ceil(EN/NBH)
#define NBS 250      // scatter chunks
#define CHS 4000     // EN / NBS exact
#define NBT 40       // z-transpose blocks (250 rows each)
#define RPT 250      // rows per transpose block

struct Ctrl { int done; int pad; };

// ragged L^T quad tables
__constant__ int QK[40] = {0,0,0,0, 1,1,1,1, 2,2,2,2, 3,3,3,3,
                           4,4,4, 5,5,5, 6,6,6, 7,7,7,
                           8,8, 9,9, 10,10, 11,11, 12, 13, 14, 15};
__constant__ int QQ[40] = {0,1,2,3, 0,1,2,3, 0,1,2,3, 0,1,2,3,
                           1,2,3, 1,2,3, 1,2,3, 1,2,3,
                           2,3, 2,3, 2,3, 2,3, 3, 3, 3, 3};

// offset of k's first quad within the ragged block (compile-time foldable)
__host__ __device__ __forceinline__ constexpr int offk(int k) {
    return (k < 4) ? k * 4
         : (k < 8) ? 16 + (k - 4) * 3
         : (k < 12) ? 28 + (k - 8) * 2
         : 36 + (k - 12);
}

// ---------- tiny histogram kernel (scatter's only dependency) --------------
// gcnt must be zeroed before this kernel.
__global__ __launch_bounds__(256) void hist_k(
    const int* __restrict__ mc, int* __restrict__ gcnt)
{
    __shared__ int h[COLN];
    const int tid = threadIdx.x;
    for (int i = tid; i < COLN; i += 256) h[i] = 0;
    __syncthreads();
    const int lo = blockIdx.x * CHH, hi = min(lo + CHH, EN);
    for (int e = lo + tid; e < hi; e += 256)
        atomicAdd(&h[mc[e]], 1);
    __syncthreads();
    for (int i = tid; i < COLN; i += 256) {
        int v = h[i];
        if (v) atomicAdd(&gcnt[i], v);
    }
}

// ---------- mid kernel: scatter (+redundant scan) + transpose + records ----
// Transpose/record blocks are independent filler hidden under scatter time.
__global__ __launch_bounds__(512) void mid_k(
    const int* __restrict__ mr, const int* __restrict__ mc,
    const int* __restrict__ yy, const int* __restrict__ gcnt,
    int* __restrict__ gcur, int* __restrict__ gbase,
    int* __restrict__ packed,
    const float* __restrict__ z_rows, const float* __restrict__ z_cols,
    const float* __restrict__ gamma_cols, const float* __restrict__ L,
    const float* __restrict__ col_times, const int* __restrict__ col_idx_list,
    float* __restrict__ rec, float* __restrict__ zt)
{
    const int tid = threadIdx.x;
    if (blockIdx.x < NBS) {
        // ================= scatter =================
        __shared__ int bases[COLN];
        __shared__ int lh[COLN];
        __shared__ int sums[512];

        // tight exclusive scan of the 4096 counts (redundant per block)
        int s = 0;
        #pragma unroll
        for (int i = 0; i < 8; ++i) {
            int c = tid * 8 + i;
            int v = gcnt[c];
            bases[c] = v;
            s += v;
        }
        sums[tid] = s;
        __syncthreads();
        for (int off = 1; off < 512; off <<= 1) {
            int v = (tid >= off) ? sums[tid - off] : 0;
            __syncthreads();
            sums[tid] += v;
            __syncthreads();
        }
        int run = (tid == 0) ? 0 : sums[tid - 1];
        #pragma unroll
        for (int i = 0; i < 8; ++i) {
            int c = tid * 8 + i;
            int v = bases[c];
            bases[c] = run;
            run += v;
        }
        if (blockIdx.x == 0) {     // publish for edge kernel
            #pragma unroll
            for (int i = 0; i < 8; ++i) { int c = tid * 8 + i; gbase[c] = bases[c]; }
        }

        // per-chunk local histogram
        for (int i = tid; i < COLN; i += 512) lh[i] = 0;
        __syncthreads();
        const int lo = blockIdx.x * CHS, hi = min(lo + CHS, EN);
        for (int e = lo + tid; e < hi; e += 512)
            atomicAdd(&lh[mc[e]], 1);
        __syncthreads();

        // reserve global ranges (gcur = offset-from-base, zeroed by memset)
        for (int i = tid; i < COLN; i += 512) {
            int cntl = lh[i];
            if (cntl) lh[i] = bases[i] + atomicAdd(&gcur[i], cntl);
        }
        __syncthreads();

        // place: 14 bits row + 3 bits y
        for (int e = lo + tid; e < hi; e += 512) {
            int c = mc[e];
            int pos = atomicAdd(&lh[c], 1);
            packed[pos] = mr[e] | (yy[e] << 14);
        }
    } else if (blockIdx.x < NBS + NBT) {
        // ================= transpose z_rows [4][ROW][16] -> zt [ROW][4][16] =====
        const int r0 = (blockIdx.x - NBS) * RPT;
        const size_t SL = (size_t)ROWN * DIM;
        float4* dst = (float4*)zt;
        #pragma unroll
        for (int v = 0; v < 4; ++v) {
            const float4* src = (const float4*)(z_rows + (size_t)v * SL
                                                + (size_t)r0 * DIM);
            for (int idx = tid; idx < RPT * 4; idx += 512) {
                const int r = idx >> 2, q = idx & 3;
                dst[(size_t)(r0 + r) * 16 + v * 4 + q] = src[idx];
            }
        }
    } else {
        // ================= per-column record =================
        __shared__ float Lsh[DIM][DIM + 1];
        const int c = blockIdx.x - (NBS + NBT);
        const int cidx = col_idx_list[c];
        if (tid < 256) Lsh[tid >> 4][tid & 15] = L[(size_t)cidx * 256 + tid];
        __syncthreads();

        float4* r = (float4*)(rec + (size_t)c * RECF);
        if (tid < 40) {
            const int k = QK[tid];
            const int d = 4 * QQ[tid];
            r[1 + tid] = make_float4(Lsh[d][k], Lsh[d+1][k], Lsh[d+2][k], Lsh[d+3][k]);
        } else if (tid < 44) {
            const int j = tid - 40;
            const float* zp = z_cols + (size_t)c * DIM + 4 * j;
            r[41 + j] = make_float4(zp[0], zp[1], zp[2], zp[3]);
        } else if (tid == 44) {
            const float t = col_times[c];
            r[0]  = make_float4(1.0f, t, 0.5f * t * t, t * t * t * (1.0f / 6.0f));
            r[45] = make_float4(gamma_cols[c], 0.0f, 0.0f, 0.0f);
        }
    }
}

// log( Phi(hi) - Phi(lo) ), cancellation-free, branch-light, always finite.
__device__ __forceinline__ float log_cdf_diff_f(float hi, float lo) {
    const float r = 0.70710678118654752440f;
    if (hi + lo < 0.0f) { float t = hi; hi = -lo; lo = -t; }
    float d = erfcf(lo * r) - erfcf(hi * r);
    return logf(0.5f * fmaxf(d, 1e-37f));
}

// full per-edge math given the 16 pre-loaded z quads (stays in regs via SROA)
__device__ __forceinline__ double edge_ll(
    const float4 a[16], const float4* __restrict__ R,
    float tp1, float tp2, float tp3,
    float4 zc0, float4 zc1, float4 zc2, float4 zc3,
    float ga, float gcol, int yv, const float* __restrict__ th, float inv_s)
{
    float d_[DIM];
    #pragma unroll
    for (int q = 0; q < 4; ++q) {
        const float4 zc = (q == 0) ? zc0 : (q == 1) ? zc1 : (q == 2) ? zc2 : zc3;
        d_[4*q+0] = fmaf(a[12+q].x, tp3, fmaf(a[8+q].x, tp2, fmaf(a[4+q].x, tp1, a[q].x))) - zc.x;
        d_[4*q+1] = fmaf(a[12+q].y, tp3, fmaf(a[8+q].y, tp2, fmaf(a[4+q].y, tp1, a[q].y))) - zc.y;
        d_[4*q+2] = fmaf(a[12+q].z, tp3, fmaf(a[8+q].z, tp2, fmaf(a[4+q].z, tp1, a[q].z))) - zc.z;
        d_[4*q+3] = fmaf(a[12+q].w, tp3, fmaf(a[8+q].w, tp2, fmaf(a[4+q].w, tp1, a[q].w))) - zc.w;
    }
    float nsq = 0.0f;
    #pragma unroll
    for (int k = 0; k < DIM; ++k) {
        const int q0 = k >> 2;
        float t = 0.0f;
        #pragma unroll
        for (int q = q0; q < 4; ++q) {
            const float4 lv = R[1 + offk(k) + (q - q0)];
            t = fmaf(lv.x, d_[4*q+0],
                fmaf(lv.y, d_[4*q+1],
                fmaf(lv.z, d_[4*q+2],
                fmaf(lv.w, d_[4*q+3], t))));
        }
        nsq = fmaf(t, t, nsq);
    }
    const float f = ga + gcol - sqrtf(nsq);
    return (double)log_cdf_diff_f((th[yv] - f) * inv_s,
                                  (th[yv - 1] - f) * inv_s);
}

// ---------- edge kernel: 1 col/block, 2-edge ILP, fused finalize -----------
__global__ __launch_bounds__(128, 2) void edge6(
    const float* __restrict__ zt, const float* __restrict__ gamma_rows,
    const float4* __restrict__ rec4, const float* __restrict__ b,
    const float* __restrict__ sigma, const int* __restrict__ packed,
    const int* __restrict__ gbase, const int* __restrict__ gcnt,
    Ctrl* __restrict__ ctrl, double* __restrict__ bsum,
    float* __restrict__ out)
{
    __shared__ float4 R[RECQ];
    __shared__ float th[6];
    __shared__ double wsum[2];
    __shared__ int lastf;
    const int c = blockIdx.x;
    const int tid = threadIdx.x;
    if (tid < RECQ) R[tid] = rec4[(size_t)c * RECQ + tid];
    if (tid == 0) { th[0] = -BIGF; th[5] = BIGF; }
    if (tid < 4)  th[1 + tid] = b[tid];
    __syncthreads();

    const float inv_s = 1.0f / sigma[0];
    const int base = gbase[c];
    const int end  = base + gcnt[c];
    const float4 t0 = R[0];
    const float tp1 = t0.y, tp2 = t0.z, tp3 = t0.w;
    const float4 zc0 = R[41], zc1 = R[42], zc2 = R[43], zc3 = R[44];
    const float gcol = R[45].x;

    double acc = 0.0;
    int i1 = base + tid;
    int i2 = i1 + 128;
    bool v1 = i1 < end;
    bool v2 = i2 < end;
    int p1 = 0, p2 = 0;
    if (v1) p1 = packed[i1];
    if (v2) p2 = packed[i2];
    while (v1) {
        const int row1 = p1 & 0x3FFF;
        const int yv1  = (p1 >> 14) & 7;
        const int row2 = v2 ? (p2 & 0x3FFF) : row1;   // clamp -> safe loads
        const int yv2  = (p2 >> 14) & 7;
        const float ga1 = gamma_rows[row1];
        const float ga2 = gamma_rows[row2];
        const float4* __restrict__ zp1 = (const float4*)(zt + (size_t)row1 * 64);
        const float4* __restrict__ zp2 = (const float4*)(zt + (size_t)row2 * 64);

        // issue BOTH edges' z batches (32 loads in flight) before any use
        float4 a1[16], a2[16];
        #pragma unroll
        for (int j = 0; j < 16; ++j) a1[j] = zp1[j];
        #pragma unroll
        for (int j = 0; j < 16; ++j) a2[j] = zp2[j];

        // prefetch next pair's packed entries under this pair's math
        const int i1n = i1 + 256, i2n = i2 + 256;
        const bool v1n = i1n < end, v2n = i2n < end;
        int p1n = 0, p2n = 0;
        if (v1n) p1n = packed[i1n];
        if (v2n) p2n = packed[i2n];

        acc += edge_ll(a1, R, tp1, tp2, tp3, zc0, zc1, zc2, zc3,
                       ga1, gcol, yv1, th, inv_s);
        if (v2)
            acc += edge_ll(a2, R, tp1, tp2, tp3, zc0, zc1, zc2, zc3,
                           ga2, gcol, yv2, th, inv_s);

        i1 = i1n; i2 = i2n; v1 = v1n; v2 = v2n; p1 = p1n; p2 = p2n;
    }

    #pragma unroll
    for (int off = 32; off > 0; off >>= 1) acc += __shfl_down(acc, off, 64);
    const int lane = tid & 63;
    const int wid  = tid >> 6;
    if (lane == 0) wsum[wid] = acc;
    __syncthreads();
    if (tid == 0) {
        bsum[c] = wsum[0] + wsum[1];         // plain store, no contention
        __threadfence();
        const int old = atomicAdd(&ctrl->done, 1);
        lastf = (old == COLN - 1);
    }
    __syncthreads();
    if (lastf) {
        __threadfence();
        double a2s = 0.0;
        #pragma unroll
        for (int j = 0; j < COLN / 128; ++j) a2s += bsum[tid + j * 128];
        #pragma unroll
        for (int off = 32; off > 0; off >>= 1) a2s += __shfl_down(a2s, off, 64);
        if (lane == 0) wsum[wid] = a2s;
        __syncthreads();
        if (tid == 0) out[0] = -(float)(wsum[0] + wsum[1]);
    }
}

extern "C" void kernel_launch(void* const* d_in, const int* in_sizes, int n_in,
                              void* d_out, int out_size, void* d_ws, size_t ws_size,
                              hipStream_t stream) {
    const float* z_rows       = (const float*)d_in[0];
    const float* z_cols       = (const float*)d_in[1];
    const float* gamma_rows   = (const float*)d_in[2];
    const float* gamma_cols   = (const float*)d_in[3];
    const float* L            = (const float*)d_in[4];
    const float* b            = (const float*)d_in[5];
    const float* sigma        = (const float*)d_in[6];
    const float* col_times    = (const float*)d_in[7];
    const int*   mat_rows     = (const int*)d_in[8];
    const int*   mat_cols     = (const int*)d_in[9];
    const int*   y            = (const int*)d_in[10];
    const int*   col_idx_list = (const int*)d_in[11];

    // workspace layout (16B aligned):
    //   rec   : 3,145,728 B   @ 0
    //   zt    : 2,560,000 B   @ 3,145,728
    //   gcnt  : 16,384 B      @ 5,705,728   \
    //   gcur  : 16,384 B      @ 5,722,112    } one memset (gcnt+gcur+ctrl)
    //   ctrl  : 128 B         @ 5,738,496   /
    //   gbase : 16,384 B      @ 5,738,624
    //   bsum  : 32,768 B      @ 5,755,008
    //   pk    : 4,000,000 B   @ 5,787,776   (total 9,787,776 B)
    char* ws = (char*)d_ws;
    float*  rec   = (float*)ws;
    float*  zt    = (float*)(ws + 3145728);
    int*    gcnt  = (int*)(ws + 5705728);
    int*    gcur  = (int*)(ws + 5722112);
    Ctrl*   ctrl  = (Ctrl*)(ws + 5738496);
    int*    gbase = (int*)(ws + 5738624);
    double* bsum  = (double*)(ws + 5755008);
    int*    pk    = (int*)(ws + 5787776);

    hipMemsetAsync(gcnt, 0, 2 * 16384 + 128, stream);   // gcnt + gcur + ctrl
    hist_k<<<NBH, 256, 0, stream>>>(mat_cols, gcnt);
    mid_k<<<NBS + NBT + COLN, 512, 0, stream>>>(
        mat_rows, mat_cols, y, gcnt, gcur, gbase, pk,
        z_rows, z_cols, gamma_cols, L, col_times, col_idx_list, rec, zt);
    edge6<<<COLN, 128, 0, stream>>>(zt, gamma_rows, (const float4*)rec,
                                    b, sigma, pk, gbase, gcnt, ctrl, bsum,
                                    (float*)d_out);
}